// Round 6
// baseline (91.805 us; speedup 1.0000x reference)
//
#include <hip/hip_runtime.h>
#include <math.h>

#define NQ 12
#define NL 4
#define NC 10
#define NB 512
#define BN_EPS 1e-5f

typedef float v2f __attribute__((ext_vector_type(2)));

// Packed complex 2x2 butterfly; constants pre-paired:
// c0={m0,m0} c1={-m1,m1} c2={m2,m2} c3={-m3,m3} (row0), c4..c7 row1.
__device__ __forceinline__ void bfly(v2f& A, v2f& B,
    v2f c0, v2f c1, v2f c2, v2f c3, v2f c4, v2f c5, v2f c6, v2f c7)
{
    const v2f As = A.yx, Bs = B.yx;
    const v2f An = __builtin_elementwise_fma(c0, A,
                   __builtin_elementwise_fma(c1, As,
                   __builtin_elementwise_fma(c2, B, c3 * Bs)));
    const v2f Bn = __builtin_elementwise_fma(c4, A,
                   __builtin_elementwise_fma(c5, As,
                   __builtin_elementwise_fma(c6, B, c7 * Bs)));
    A = An; B = Bn;
}

// Precompute all 512x48 fused (Rot*RY) gate matrices into d_ws (pre-paired).
__global__ __launch_bounds__(256) void gates_kernel(
    const float* __restrict__ x, const float* __restrict__ w,
    float* __restrict__ gates)
{
    const int idx = blockIdx.x * 256 + threadIdx.x;
    if (idx >= NB * 48) return;
    const int b = idx / 48, g = idx % 48;
    const int q = g % NQ;
    const float xq = 0.5f * x[b*NQ + q];
    const float cx = cosf(xq), sx = sinf(xq);
    const int wi = g*3;
    const float phi = w[wi], tht = w[wi+1], om = w[wi+2];
    const float ct = cosf(0.5f*tht), st = sinf(0.5f*tht);
    const float aa = 0.5f*(phi + om), dd = 0.5f*(phi - om);
    const float ca = cosf(aa), sa = sinf(aa);
    const float cd = cosf(dd), sd = sinf(dd);
    const float u00r =  ca*ct, u00i = -sa*ct;
    const float u01r = -cd*st, u01i = -sd*st;
    const float u10r =  cd*st, u10i = -sd*st;
    const float u11r =  ca*ct, u11i =  sa*ct;
    const float m00r = u00r*cx + u01r*sx, m00i = u00i*cx + u01i*sx;
    const float m01r = u01r*cx - u00r*sx, m01i = u01i*cx - u00i*sx;
    const float m10r = u10r*cx + u11r*sx, m10i = u10i*cx + u11i*sx;
    const float m11r = u11r*cx - u10r*sx, m11i = u11i*cx - u10i*sx;
    float* gp = gates + (size_t)idx * 16;
    gp[0]  =  m00r; gp[1]  = m00r;  gp[2]  = -m00i; gp[3]  = m00i;
    gp[4]  =  m01r; gp[5]  = m01r;  gp[6]  = -m01i; gp[7]  = m01i;
    gp[8]  =  m10r; gp[9]  = m10r;  gp[10] = -m10i; gp[11] = m10i;
    gp[12] =  m11r; gp[13] = m11r;  gp[14] = -m11i; gp[15] = m11i;
}

// A-layout slot map: region j[11:9], x = j[8:0]^73*region, psi(x)=x^(x>>4).
// GF(2)-linear in j => per-r ring-CNOT offsets fold to constants.
__device__ __forceinline__ unsigned slotA(unsigned j) {
    const unsigned v = j >> 9, x = (j & 511u) ^ (73u * v);
    return (v << 9) | (x ^ (x >> 4));
}
// Ring-CNOT per-r index delta d(r) (j = base_j ^ d(r)).
__device__ __forceinline__ unsigned dA(int r) {
    const unsigned p  = (0x96u >> r) & 1u;            // parity(r)
    const unsigned e2 = ((unsigned)r >> 2) & 1u;
    const unsigned e1 = e2 ^ (((unsigned)r >> 1) & 1u);
    const unsigned e0 = e1 ^ ((unsigned)r & 1u);
    return (p << 11) | (e2 << 2) | (e1 << 1) | e0;
}

// 512 threads/block, 8 amps/thread (3 local qubits), 4 stages/layer.
// Layouts (i = 12-bit state index; qubit q <-> bit 11-q):
//  A: i=(r<<9)|t   B: i[8:6]=r  C: i[5:3]=r  D: i[2:0]=r  (rest = t bits in order)
// Transition slot schemes verified by hand on concrete (t,r) examples.
__global__ __launch_bounds__(512, 4) void vqc_kernel(
    const float* __restrict__ gates, const float* __restrict__ bias,
    float* __restrict__ probs)
{
    __shared__ v2f buf[2][4096];                  // 2 x 32 KB staging
    __shared__ float red[8*NC];

    const int b = blockIdx.x;
    const int t = threadIdx.x;
    const v2f* gcp = (const v2f*)(gates + (size_t)b * 768);   // uniform -> s_load

    const int w = t >> 6, lane = t & 63;
    const int lane53 = (t >> 3) & 7, lane20 = t & 7;
    const unsigned baseAB = ((unsigned)w << 9) | ((unsigned)lane ^ (73u * w));
    const unsigned baseBC = ((unsigned)lane53 << 9)
                          | ((((unsigned)w << 6) | (unsigned)lane20) ^ (73u * lane53));
    const unsigned baseCD = ((unsigned)lane20 << 9)
                          | ((((unsigned)w << 6) | ((unsigned)lane53 << 3)) ^ (73u * lane20));

    // suffix parities of t: Qk = parity(t>>k)
    const unsigned t8 = (t >> 8) & 1u;
    const unsigned Q8 = t8;
    const unsigned Q7 = Q8 ^ ((t >> 7) & 1u);
    const unsigned Q6 = Q7 ^ ((t >> 6) & 1u);
    const unsigned Q5 = Q6 ^ ((t >> 5) & 1u);
    const unsigned Q4 = Q5 ^ ((t >> 4) & 1u);
    const unsigned Q3 = Q4 ^ ((t >> 3) & 1u);
    const unsigned Q2 = Q3 ^ ((t >> 2) & 1u);
    const unsigned Q1 = Q2 ^ ((t >> 1) & 1u);
    const unsigned Q0 = Q1 ^ (t & 1u);
    const unsigned base_j = ((Q0 ^ t8) << 11) | (Q7 << 10) | (Q6 << 9) | (Q5 << 8)
                          | (Q4 << 7) | (Q3 << 6) | (Q2 << 5) | (Q1 << 4) | (Q0 * 0xFu);
    const unsigned baseDA = slotA(base_j);

    v2f a[8];
    #pragma unroll
    for (int r = 0; r < 8; ++r) a[r] = (v2f){0.f, 0.f};
    if (t == 0) a[0].x = 1.f;

    // gate on r-bit (1<<g) in stage s uses gm[l*12 + 3s + 2 - g]
    #define GATE(gi, bit) { \
        const v2f* cp = gcp + (gi)*8; \
        const v2f c0=cp[0],c1=cp[1],c2=cp[2],c3=cp[3], \
                  c4=cp[4],c5=cp[5],c6=cp[6],c7=cp[7]; \
        _Pragma("unroll") \
        for (int r0 = 0; r0 < 8; ++r0) \
            if (!(r0 & (bit))) bfly(a[r0], a[r0|(bit)], c0,c1,c2,c3,c4,c5,c6,c7); \
    }
    #define STAGE3(base) GATE((base)+2, 1) GATE((base)+1, 2) GATE((base)+0, 4)

    int pb = 0;
    #pragma unroll
    for (int l = 0; l < NL; ++l) {
        STAGE3(l*12 + 0)                       // qubits 0-2 (A-local)
        {   // A -> B
            v2f* bp = buf[pb]; pb ^= 1;
            #pragma unroll
            for (int r = 0; r < 8; ++r) bp[baseAB ^ ((unsigned)r << 6)] = a[r];
            __syncthreads();
            #pragma unroll
            for (int r = 0; r < 8; ++r)
                a[r] = bp[((unsigned)r << 9) | ((unsigned)t ^ (73u * r))];
        }
        STAGE3(l*12 + 3)                       // qubits 3-5 (B-local)
        {   // B -> C
            v2f* bp = buf[pb]; pb ^= 1;
            #pragma unroll
            for (int r = 0; r < 8; ++r) bp[baseBC ^ ((unsigned)r << 3)] = a[r];
            __syncthreads();
            #pragma unroll
            for (int r = 0; r < 8; ++r)
                a[r] = bp[((unsigned)r << 9) | ((unsigned)t ^ (73u * r))];
        }
        STAGE3(l*12 + 6)                       // qubits 6-8 (C-local)
        {   // C -> D
            v2f* bp = buf[pb]; pb ^= 1;
            #pragma unroll
            for (int r = 0; r < 8; ++r) bp[baseCD ^ (unsigned)r] = a[r];
            __syncthreads();
            #pragma unroll
            for (int r = 0; r < 8; ++r)
                a[r] = bp[((unsigned)r << 9) | ((unsigned)t ^ (73u * r))];
        }
        STAGE3(l*12 + 9)                       // qubits 9-11 (D-local)
        if (l < NL-1) {
            // D -> A' with ring-CNOT permutation fused (slotA is GF2-linear)
            v2f* bp = buf[pb]; pb ^= 1;
            #pragma unroll
            for (int r = 0; r < 8; ++r) bp[baseDA ^ slotA(dA(r))] = a[r];
            __syncthreads();
            #pragma unroll
            for (int r = 0; r < 8; ++r) {
                const unsigned xx = (unsigned)t ^ (73u * r);
                a[r] = bp[((unsigned)r << 9) | (xx ^ (xx >> 4))];
            }
        }
    }

    // ---- readout: i = (t<<3)|r in D-layout; signs = bits of j = M(i) ----
    const float S0 = (Q0 ^ t8) ? -1.f : 1.f;   // j_11 base, flip by parity(r)
    const float S1 = Q7 ? -1.f : 1.f;          // j_10
    const float S2 = Q6 ? -1.f : 1.f;          // j_9
    const float S3 = Q5 ? -1.f : 1.f;          // j_8
    const float S4 = Q4 ? -1.f : 1.f;          // j_7
    const float S5 = Q3 ? -1.f : 1.f;          // j_6
    const float S6 = Q2 ? -1.f : 1.f;          // j_5
    const float S7 = Q1 ? -1.f : 1.f;          // j_4
    const float S8 = Q0 ? -1.f : 1.f;          // j_3
    const float S9 = Q0 ? -1.f : 1.f;          // j_2 base, flip by r2

    float acc[NC];
    #pragma unroll
    for (int c = 0; c < NC; ++c) acc[c] = 0.f;
    #pragma unroll
    for (int r = 0; r < 8; ++r) {
        const float p = a[r].x*a[r].x + a[r].y*a[r].y;
        const int par = (0x96 >> r) & 1;
        const int r2  = (r >> 2) & 1;
        acc[0] += (par ? -S0 : S0) * p;
        acc[1] += S1 * p;
        acc[2] += S2 * p;
        acc[3] += S3 * p;
        acc[4] += S4 * p;
        acc[5] += S5 * p;
        acc[6] += S6 * p;
        acc[7] += S7 * p;
        acc[8] += S8 * p;
        acc[9] += (r2 ? -S9 : S9) * p;
    }
    #pragma unroll
    for (int off = 32; off >= 1; off >>= 1) {
        #pragma unroll
        for (int c = 0; c < NC; ++c)
            acc[c] += __shfl_down(acc[c], off, 64);
    }
    if (lane == 0) {
        #pragma unroll
        for (int c = 0; c < NC; ++c) red[w*NC + c] = acc[c];
    }
    __syncthreads();
    if (t == 0) {
        float ez[NC];
        float mx = -1e30f;
        #pragma unroll
        for (int c = 0; c < NC; ++c) {
            float s = 0.f;
            #pragma unroll
            for (int k = 0; k < 8; ++k) s += red[k*NC + c];
            ez[c] = s + bias[c];
            mx = fmaxf(mx, ez[c]);
        }
        float sum = 0.f;
        #pragma unroll
        for (int c = 0; c < NC; ++c) { ez[c] = expf(ez[c] - mx); sum += ez[c]; }
        const float inv = 1.f / sum;
        #pragma unroll
        for (int c = 0; c < NC; ++c) probs[b*NC + c] = ez[c] * inv;
    }
}

// BatchNorm1d (training mode, biased var) over the batch dim, in place on d_out.
__global__ __launch_bounds__(256) void bn_kernel(
    float* __restrict__ probs, const float* __restrict__ gamma,
    const float* __restrict__ beta)
{
    const int c = blockIdx.x;
    const int t = threadIdx.x;
    const float v0 = probs[t*NC + c];
    const float v1 = probs[(t + 256)*NC + c];
    float s  = v0 + v1;
    float ss = v0*v0 + v1*v1;
    #pragma unroll
    for (int off = 32; off >= 1; off >>= 1) {
        s  += __shfl_down(s,  off, 64);
        ss += __shfl_down(ss, off, 64);
    }
    __shared__ float sm[8];
    __shared__ float stat[2];
    const int wave = t >> 6, lanei = t & 63;
    if (lanei == 0) { sm[wave] = s; sm[4 + wave] = ss; }
    __syncthreads();
    if (t == 0) {
        const float S  = sm[0] + sm[1] + sm[2] + sm[3];
        const float SS = sm[4] + sm[5] + sm[6] + sm[7];
        const float mu  = S * (1.f/512.f);
        const float var = SS * (1.f/512.f) - mu*mu;
        stat[0] = mu;
        stat[1] = 1.f / sqrtf(var + BN_EPS);
    }
    __syncthreads();
    const float mu = stat[0], inv = stat[1];
    const float g = gamma[c], bt = beta[c];
    probs[t*NC + c]         = (v0 - mu) * inv * g + bt;
    probs[(t + 256)*NC + c] = (v1 - mu) * inv * g + bt;
}

extern "C" void kernel_launch(void* const* d_in, const int* in_sizes, int n_in,
                              void* d_out, int out_size, void* d_ws, size_t ws_size,
                              hipStream_t stream) {
    const float* x     = (const float*)d_in[0];   // (512, 12)
    const float* w     = (const float*)d_in[1];   // (4, 12, 3)
    const float* bias  = (const float*)d_in[2];   // (10,)
    const float* gamma = (const float*)d_in[3];   // (10,)
    const float* beta  = (const float*)d_in[4];   // (10,)
    float* out   = (float*)d_out;                 // (512, 10) float32
    float* gates = (float*)d_ws;                  // 512*48*16 floats = 1.57 MB

    gates_kernel<<<(NB*48 + 255)/256, 256, 0, stream>>>(x, w, gates);
    vqc_kernel<<<NB, 512, 0, stream>>>(gates, bias, out);
    bn_kernel<<<NC, 256, 0, stream>>>(out, gamma, beta);
}